// Round 13
// baseline (133.313 us; speedup 1.0000x reference)
//
#include <hip/hip_runtime.h>

// Continuity loss, neighbor=3, X = (8192, 4096) fp32 row-major.
// loss = -(1/R) * sum_{i=1,2} sum_{j=0,1,2} |X[r,c]X[r+i,c+j]| ln|X[r,c]X[r+i,c+j]|
//
// Identity: u=|x|, w=u*log2(u)  ->  |ab| ln|ab| = ln2*(w_a*u_b + u_a*w_b).
// One v_log_f32 per element-slot; 6 pair terms factor into sliding column
// sums Su/Sw over rows r+1, r+2.
//
// Ledger: R3 pipeline 29.6 | R4 fusion 64.8 X | R5 shfl-halo 51.2 X |
// R6 cap(256,4) 29.5 | R7 no-fmax NaN X | R8 cap+PF4 49.3 X | R9 PF4 30.7
// null | R10 8-col 31.1 null | R11 atomic-fusion 38.1 X | R12 H=64 27.4 WIN
// (block count 1024->512: prologue fill + block events are real cost).
// R13: H=128 (256 blocks, 1 block/CU). Same hot loop. Pre-registered:
// null/loss => revert to R12 and declare roofline.

constexpr int C  = 4096;
constexpr int CQ = C / 4;   // 1024 quads per row
constexpr int H  = 128;     // base rows per strip
constexpr int NT = 256;
constexpr int PF = 3;       // prefetch depth (raw slots)

__global__ __launch_bounds__(NT) void closs_partial(const float* __restrict__ X,
                                                    float* __restrict__ part, int R) {
    const int cq  = (blockIdx.x & 3) * NT + threadIdx.x;  // 0..1023
    const int r0  = (blockIdx.x >> 2) * H;
    const bool halo = (cq < CQ - 1);                      // last quad has no cols c+4,c+5
    const size_t col = (size_t)cq << 2;

    float raw[PF][6];
    float u[3][6], w[3][6];

    // unconditional, address-clamped row load into a raw slot
    auto load_row = [&](int rr, float* dst) {
        int rabs = r0 + rr;
        int rcl  = rabs < R ? rabs : R - 1;            // block-uniform clamp, no OOB
        const float* p  = X + (size_t)rcl * C + col;
        *reinterpret_cast<float4*>(dst) = *reinterpret_cast<const float4*>(p);
        const float* ph = halo ? p + 4 : X;            // safe dummy addr for last quad
        float2 h = *reinterpret_cast<const float2*>(ph);
        dst[4] = h.x;
        dst[5] = h.y;
    };

    // raw -> (u, w); invalid rows (>= R) and halo-less lanes forced to zero
    auto uw_row = [&](const float* src, float* uu, float* ww, bool valid) {
#pragma unroll
        for (int k = 0; k < 6; ++k) {
            float a = fabsf(src[k]);
            if (k >= 4 && !halo) a = 0.0f;
            if (!valid) a = 0.0f;
            uu[k] = a;
            // fmax guard REQUIRED: zeroed halo/row lanes would give
            // 0*log2(0) = NaN without it (R7 failure). a==0 -> w==0 with it.
            ww[k] = a * __log2f(fmaxf(a, 1e-37f));
        }
    };

    // prologue: rows 0,1 -> u/w bufs; slots then hold rows 2,3,4 in flight
    load_row(0, raw[0]);
    load_row(1, raw[1]);
    load_row(2, raw[2]);
    uw_row(raw[0], u[0], w[0], true);   // r0   < R always
    uw_row(raw[1], u[1], w[1], true);   // r0+1 < R always (H >= 2)
    load_row(3, raw[0]);
    load_row(4, raw[1]);

    float acc = 0.0f;
#pragma unroll
    for (int rr = 0; rr < H; ++rr) {
        const int i0 = rr % 3, i1 = (rr + 1) % 3, i2 = (rr + 2) % 3;  // static
        // consume oldest in-flight row (rr+2), then refill its slot with rr+5
        uw_row(raw[(rr + 2) % PF], u[i2], w[i2], r0 + rr + 2 < R);
        if (rr + 5 <= H + 1) load_row(rr + 5, raw[(rr + 5) % PF]);

        float csu[6], csw[6];
#pragma unroll
        for (int k = 0; k < 6; ++k) {
            csu[k] = u[i1][k] + u[i2][k];
            csw[k] = w[i1][k] + w[i2][k];
        }
#pragma unroll
        for (int k = 0; k < 4; ++k) {
            float Su = csu[k] + csu[k + 1] + csu[k + 2];
            float Sw = csw[k] + csw[k + 1] + csw[k + 2];
            acc = fmaf(w[i0][k], Su, fmaf(u[i0][k], Sw, acc));
        }
    }

    // wave shuffle reduction + LDS across 4 waves
#pragma unroll
    for (int off = 32; off > 0; off >>= 1) acc += __shfl_down(acc, off, 64);
    __shared__ float wsum[NT / 64];
    const int lane = threadIdx.x & 63;
    const int wid  = threadIdx.x >> 6;
    if (lane == 0) wsum[wid] = acc;
    __syncthreads();
    if (threadIdx.x == 0) {
        float s = 0.0f;
#pragma unroll
        for (int ww = 0; ww < NT / 64; ++ww) s += wsum[ww];
        part[blockIdx.x] = s;
    }
}

__global__ __launch_bounds__(256) void closs_final(const float* __restrict__ part,
                                                   float* __restrict__ out, int n,
                                                   double scale) {
    double s = 0.0;
    for (int i = threadIdx.x; i < n; i += 256) s += (double)part[i];
#pragma unroll
    for (int off = 32; off > 0; off >>= 1) s += __shfl_down(s, off, 64);
    __shared__ double wsum[4];
    const int lane = threadIdx.x & 63;
    const int wid  = threadIdx.x >> 6;
    if (lane == 0) wsum[wid] = s;
    __syncthreads();
    if (threadIdx.x == 0) {
        double t = wsum[0] + wsum[1] + wsum[2] + wsum[3];
        out[0] = (float)(t * scale);
    }
}

extern "C" void kernel_launch(void* const* d_in, const int* in_sizes, int n_in,
                              void* d_out, int out_size, void* d_ws, size_t ws_size,
                              hipStream_t stream) {
    const float* X = (const float*)d_in[0];
    const int R = in_sizes[0] / C;            // 8192
    const int nblocks = (R / H) * (CQ / NT);  // 64 * 4 = 256

    float* part = (float*)d_ws;               // nblocks floats

    closs_partial<<<nblocks, NT, 0, stream>>>(X, part, R);

    const double scale = -0.69314718055994530942 / (double)R;
    closs_final<<<1, 256, 0, stream>>>(part, (float*)d_out, nblocks, scale);
}

// Round 14
// 27.361 us; speedup vs baseline: 4.8723x; 4.8723x over previous
//
#include <hip/hip_runtime.h>

// Continuity loss, neighbor=3, X = (8192, 4096) fp32 row-major.
// loss = -(1/R) * sum_{i=1,2} sum_{j=0,1,2} |X[r,c]X[r+i,c+j]| ln|X[r,c]X[r+i,c+j]|
//
// Identity: u=|x|, w=u*log2(u)  ->  |ab| ln|ab| = ln2*(w_a*u_b + u_a*w_b).
// One v_log_f32 per element-slot; 6 pair terms factor into sliding column
// sums Su/Sw over rows r+1, r+2.
//
// Ledger: R3 pipeline 29.6 | R4 fusion 64.8 X | R5 shfl-halo 51.2 X |
// R6 cap(256,4) 29.5 | R7 no-fmax NaN X | R8 cap+PF4 49.3 X | R9 PF4 30.7
// null | R10 8-col 31.1 null | R11 atomic-fusion 38.1 X | R12 H=64 27.4 BEST
// | R13 H=128 133 X (unrolled pipeline spilled: VGPR 236 + 18.9KB LDS).
// R14: pre-registered revert to R12 exactly (H=64, 512 blocks).

constexpr int C  = 4096;
constexpr int CQ = C / 4;   // 1024 quads per row
constexpr int H  = 64;      // base rows per strip
constexpr int NT = 256;
constexpr int PF = 3;       // prefetch depth (raw slots)

__global__ __launch_bounds__(NT) void closs_partial(const float* __restrict__ X,
                                                    float* __restrict__ part, int R) {
    const int cq  = (blockIdx.x & 3) * NT + threadIdx.x;  // 0..1023
    const int r0  = (blockIdx.x >> 2) * H;
    const bool halo = (cq < CQ - 1);                      // last quad has no cols c+4,c+5
    const size_t col = (size_t)cq << 2;

    float raw[PF][6];
    float u[3][6], w[3][6];

    // unconditional, address-clamped row load into a raw slot
    auto load_row = [&](int rr, float* dst) {
        int rabs = r0 + rr;
        int rcl  = rabs < R ? rabs : R - 1;            // block-uniform clamp, no OOB
        const float* p  = X + (size_t)rcl * C + col;
        *reinterpret_cast<float4*>(dst) = *reinterpret_cast<const float4*>(p);
        const float* ph = halo ? p + 4 : X;            // safe dummy addr for last quad
        float2 h = *reinterpret_cast<const float2*>(ph);
        dst[4] = h.x;
        dst[5] = h.y;
    };

    // raw -> (u, w); invalid rows (>= R) and halo-less lanes forced to zero
    auto uw_row = [&](const float* src, float* uu, float* ww, bool valid) {
#pragma unroll
        for (int k = 0; k < 6; ++k) {
            float a = fabsf(src[k]);
            if (k >= 4 && !halo) a = 0.0f;
            if (!valid) a = 0.0f;
            uu[k] = a;
            // fmax guard REQUIRED: zeroed halo/row lanes would give
            // 0*log2(0) = NaN without it (R7 failure). a==0 -> w==0 with it.
            ww[k] = a * __log2f(fmaxf(a, 1e-37f));
        }
    };

    // prologue: rows 0,1 -> u/w bufs; slots then hold rows 2,3,4 in flight
    load_row(0, raw[0]);
    load_row(1, raw[1]);
    load_row(2, raw[2]);
    uw_row(raw[0], u[0], w[0], true);   // r0   < R always
    uw_row(raw[1], u[1], w[1], true);   // r0+1 < R always (H >= 2)
    load_row(3, raw[0]);
    load_row(4, raw[1]);

    float acc = 0.0f;
#pragma unroll
    for (int rr = 0; rr < H; ++rr) {
        const int i0 = rr % 3, i1 = (rr + 1) % 3, i2 = (rr + 2) % 3;  // static
        // consume oldest in-flight row (rr+2), then refill its slot with rr+5
        uw_row(raw[(rr + 2) % PF], u[i2], w[i2], r0 + rr + 2 < R);
        if (rr + 5 <= H + 1) load_row(rr + 5, raw[(rr + 5) % PF]);

        float csu[6], csw[6];
#pragma unroll
        for (int k = 0; k < 6; ++k) {
            csu[k] = u[i1][k] + u[i2][k];
            csw[k] = w[i1][k] + w[i2][k];
        }
#pragma unroll
        for (int k = 0; k < 4; ++k) {
            float Su = csu[k] + csu[k + 1] + csu[k + 2];
            float Sw = csw[k] + csw[k + 1] + csw[k + 2];
            acc = fmaf(w[i0][k], Su, fmaf(u[i0][k], Sw, acc));
        }
    }

    // wave shuffle reduction + LDS across 4 waves
#pragma unroll
    for (int off = 32; off > 0; off >>= 1) acc += __shfl_down(acc, off, 64);
    __shared__ float wsum[NT / 64];
    const int lane = threadIdx.x & 63;
    const int wid  = threadIdx.x >> 6;
    if (lane == 0) wsum[wid] = acc;
    __syncthreads();
    if (threadIdx.x == 0) {
        float s = 0.0f;
#pragma unroll
        for (int ww = 0; ww < NT / 64; ++ww) s += wsum[ww];
        part[blockIdx.x] = s;
    }
}

__global__ __launch_bounds__(256) void closs_final(const float* __restrict__ part,
                                                   float* __restrict__ out, int n,
                                                   double scale) {
    double s = 0.0;
    for (int i = threadIdx.x; i < n; i += 256) s += (double)part[i];
#pragma unroll
    for (int off = 32; off > 0; off >>= 1) s += __shfl_down(s, off, 64);
    __shared__ double wsum[4];
    const int lane = threadIdx.x & 63;
    const int wid  = threadIdx.x >> 6;
    if (lane == 0) wsum[wid] = s;
    __syncthreads();
    if (threadIdx.x == 0) {
        double t = wsum[0] + wsum[1] + wsum[2] + wsum[3];
        out[0] = (float)(t * scale);
    }
}

extern "C" void kernel_launch(void* const* d_in, const int* in_sizes, int n_in,
                              void* d_out, int out_size, void* d_ws, size_t ws_size,
                              hipStream_t stream) {
    const float* X = (const float*)d_in[0];
    const int R = in_sizes[0] / C;            // 8192
    const int nblocks = (R / H) * (CQ / NT);  // 128 * 4 = 512

    float* part = (float*)d_ws;               // nblocks floats

    closs_partial<<<nblocks, NT, 0, stream>>>(X, part, R);

    const double scale = -0.69314718055994530942 / (double)R;
    closs_final<<<1, 256, 0, stream>>>(part, (float*)d_out, nblocks, scale);
}